// Round 9
// baseline (303.618 us; speedup 1.0000x reference)
//
#include <hip/hip_runtime.h>
#include <hip/hip_bf16.h>

// B=16, T=512, E=256, A=8. Inputs f32 (+int32 mask), outputs f32:
//   d_out: [ output 16*512*256 | attn 128*512*512 ]
// R19: pair-PV phase-split. R18 (kc-outer, 4-attr batch) won 13us via 4x
// sentFB cut but paid occupancy: 67.6KB LDS -> 2 blocks/CU, so softmax/
// barrier latency went unhidden. R19 processes attrs in 2 PAIRS: per pair
// {2 sequential softmaxes -> pair-Pb(32KB) -> batched PV (bfr feeds 2
// attrs) -> epilogue -> copy-out}. Unlike failed R13 (joint softmax, two
// p[32] co-live, 144 VGPR), sequential softmax keeps one p[32] live ->
// ~116 VGPR; Sbuf = max(S 33KB, 32KB) -> ~35.3KB LDS -> 4 blocks/CU
// (enforced via __launch_bounds__(256,4)). sentFB 512KB/block (2x R12
// cut kept). acc kc-order unchanged -> bitwise-identical numerics.
// Keeps: R17-verified frag-major XwsF transport + LDS-free k_out,
// bb-major XCD swizzle, lgkm-only barriers.

#define Bt 16
#define Tt 512
#define Et 256
#define At 8

typedef __attribute__((ext_vector_type(8))) short short8;   // 8 x bf16
typedef __attribute__((ext_vector_type(4))) float floatx4;

static __device__ __forceinline__ unsigned short f2bf(float x) {
    union { float f; unsigned u; } v; v.f = x;
    unsigned r = v.u + 0x7fffu + ((v.u >> 16) & 1u);  // RNE
    return (unsigned short)(r >> 16);
}

static __device__ __forceinline__ floatx4 mfma16(short8 a, short8 b, floatx4 c) {
    return __builtin_amdgcn_mfma_f32_16x16x32_bf16(a, b, c, 0, 0, 0);
}

// Barrier that waits only on LDS ops (lgkmcnt), NOT on in-flight global
// stores (vmcnt). All barriers in k_attnpv protect LDS-only data
// (S / Pb / Xb2 / msk), so lgkm-only is sufficient (audited R11/R12/R18).
static __device__ __forceinline__ void barrier_lds() {
    __builtin_amdgcn_sched_barrier(0);
    asm volatile("s_waitcnt lgkmcnt(0)" ::: "memory");
    __builtin_amdgcn_s_barrier();
    __builtin_amdgcn_sched_barrier(0);
}

// ---- prep: sentG (Gram frags, k=e) + sentFB (PV B-frags, k=s) ------------
__global__ __launch_bounds__(256) void k_prep_sent(const float* __restrict__ sent,
                                                   unsigned short* __restrict__ sentG,
                                                   unsigned short* __restrict__ sentFB) {
    int bb = blockIdx.z;
    int s0 = blockIdx.x * 32;       // 16
    int e0 = blockIdx.y * 32;       // 8
    __shared__ float tile[32][33];
    int c  = threadIdx.x & 31;
    int r4 = threadIdx.x >> 5;
    for (int i = 0; i < 4; ++i) {
        int r = r4 + 8 * i;
        tile[r][c] = sent[(bb * Tt + s0 + r) * Et + e0 + c];
    }
    __syncthreads();
    int wv = threadIdx.x >> 6, lane = threadIdx.x & 63, quad = lane >> 4, l16 = lane & 15;
    union { short8 s; unsigned short e[8]; } u;
    if (wv < 2) {
        // sentG block (bb, st = s0/16 + wv, ec = e0/32)
#pragma unroll
        for (int j = 0; j < 8; ++j) u.e[j] = f2bf(tile[wv * 16 + l16][quad * 8 + j]);
        *(short8*)(sentG + (((size_t)(bb * 32 + (s0 >> 4) + wv)) * 8 + (e0 >> 5)) * 512
                   + lane * 8) = u.s;
    } else {
        int h = wv - 2;
        // sentFB block (bb, et = e0/16 + h, sc = s0/32)
#pragma unroll
        for (int j = 0; j < 8; ++j) u.e[j] = f2bf(tile[quad * 8 + j][h * 16 + l16]);
        *(short8*)(sentFB + (((size_t)(bb * 16 + (e0 >> 4) + h)) * 16 + (s0 >> 5)) * 512
                   + lane * 8) = u.s;
    }
}

// ---- prep: Wp (B-frag-major W), verified R9. Split over 8 y-blocks. ------
__global__ __launch_bounds__(256) void k_prep_w(const float* __restrict__ W,
                                                unsigned short* __restrict__ Wp) {
    int nt = blockIdx.x;                  // 16
    int pc = blockIdx.y;                  // 8 chunks of 2 p-iterations
    int wave = threadIdx.x >> 6, lane = threadIdx.x & 63, quad = lane >> 4, l16 = lane & 15;
    const int KK = At * Et;               // 2048
    for (int p = pc * 2; p < pc * 2 + 2; ++p) {
        int kc = wave + 4 * p;            // 64
        const float* src = W + (size_t)(nt * 16 + l16) * KK + kc * 32 + quad * 8;
        union { short8 s; unsigned short e[8]; } u;
#pragma unroll
        for (int j = 0; j < 8; ++j) u.e[j] = f2bf(src[j]);
        *(short8*)(Wp + (((size_t)nt * 64 + kc) << 9) + lane * 8) = u.s;
    }
}

// ---- fused: Gram + 2x{pair softmax + pair PV + epilogue} + frag X out ----
// 1D grid, 1024 blocks. bb-major XCD-chunked swizzle: XCD k owns bb {2k,2k+1}
// (1MB sentG+sentFB working set per XCD L2). Per block: 4 attrs in 2 pairs.
__global__ __launch_bounds__(256, 4) void k_attnpv(const unsigned short* __restrict__ sentG,
                                                   const unsigned short* __restrict__ sentFB,
                                                   const int* __restrict__ mask,
                                                   const float* __restrict__ atr,
                                                   float* __restrict__ attnf,
                                                   unsigned short* __restrict__ XwsF) {
    int hw = blockIdx.x;                        // 1024, 1024%8==0 -> bijective
    int logical = (hw & 7) * 128 + (hw >> 3);
    int bb = logical >> 6;                      // 16 (slow axis: 2 per XCD)
    int z  = (logical >> 5) & 1;                // a-group 0/1
    int t0 = (logical & 31) * 16;               // 32 tiles
    int a0 = z * 4;

    // 33 KB region: phase A = S[16][516] scores; per pair: Pb[2][8192 shorts]
    // (32 KB); epilogue: Xb2[2][4096 shorts] (16 KB, aliases Pb[0]).
    __shared__ __align__(16) float Sbuf[8256];
    __shared__ float msk[512];
    __shared__ float mrowv[16];
    unsigned short* Pb  = (unsigned short*)Sbuf;
    unsigned short* Xb2 = (unsigned short*)Sbuf;

    int tid = threadIdx.x;
    for (int i = tid; i < 512; i += 256) msk[i] = (mask[bb * Tt + i] != 0) ? 1.0f : 0.0f;
    if (tid < 16) mrowv[tid] = (mask[bb * Tt + t0 + tid] != 0) ? 1.0f : 0.0f;
    barrier_lds();

    int wv = tid >> 6, lane = tid & 63, quad = lane >> 4, l16 = lane & 15;

    // ---- Gram: A and B frags both from frag-major sentG (contiguous 1KB/wave)
    const unsigned short* Gbase = sentG + ((size_t)(bb * 32 + (t0 >> 4)) * 8) * 512 + lane * 8;
    short8 af[8];
#pragma unroll
    for (int kk = 0; kk < 8; ++kk) af[kk] = *(const short8*)(Gbase + kk * 512);

#pragma unroll
    for (int i = 0; i < 8; ++i) {
        int nt = wv * 8 + i;
        const unsigned short* Bb = sentG + ((size_t)(bb * 32 + nt) * 8) * 512 + lane * 8;
        floatx4 c = {0.f, 0.f, 0.f, 0.f};
#pragma unroll
        for (int kk = 0; kk < 8; ++kk)
            c = mfma16(af[kk], *(const short8*)(Bb + kk * 512), c);
#pragma unroll
        for (int r = 0; r < 4; ++r) {
            int cidx = nt * 16 + l16;
            Sbuf[(quad * 4 + r) * 516 + cidx] = c[r] * msk[cidx] * mrowv[quad * 4 + r];
        }
    }
    barrier_lds();

    // ---- hoist masked scores to regs; one max-reduction for all attrs
    int row = tid >> 4, cl = tid & 15;
    float w[32];
    float wmax = -1e30f;
#pragma unroll
    for (int i4 = 0; i4 < 8; ++i4) {
        float4 v = *(const float4*)&Sbuf[row * 516 + i4 * 64 + cl * 4];
        w[i4 * 4 + 0] = v.x; w[i4 * 4 + 1] = v.y; w[i4 * 4 + 2] = v.z; w[i4 * 4 + 3] = v.w;
        wmax = fmaxf(wmax, fmaxf(fmaxf(v.x, v.y), fmaxf(v.z, v.w)));
    }
#pragma unroll
    for (int off = 8; off >= 1; off >>= 1) wmax = fmaxf(wmax, __shfl_xor(wmax, off, 64));
    barrier_lds();    // all S reads done before Pb overwrites the region

    int L = (t0 >> 3) & 15;                 // t'-row base within its 16-tile

    for (int ph = 0; ph < 2; ++ph) {
        // ---- pair softmax: sequential, one p[32] live at a time ---------
#pragma unroll
        for (int ai = 0; ai < 2; ++ai) {
            int a = a0 + ph * 2 + ai;
            float av = atr[bb * At + a];
            float coef = av * av * (1.0f / 16.0f);
            float mx = coef * wmax;
            float p[32];
            float sum = 0.f;
#pragma unroll
            for (int j = 0; j < 32; ++j) {
                float e = __expf(fmaf(coef, w[j], -mx));
                p[j] = e;
                sum += e;
            }
#pragma unroll
            for (int off = 8; off >= 1; off >>= 1) sum += __shfl_xor(sum, off, 64);
            float inv = 1.0f / sum;
#pragma unroll
            for (int j = 0; j < 32; ++j) p[j] *= inv;

            // attn f32 store (coalesced) -- fire-and-forget; lgkm-only
            // barriers below do NOT drain these.
            float* orow = attnf + ((size_t)(bb * At + a) * Tt + (t0 + row)) * Tt;
#pragma unroll
            for (int i4 = 0; i4 < 8; ++i4) {
                float4 v;
                v.x = p[i4 * 4 + 0]; v.y = p[i4 * 4 + 1];
                v.z = p[i4 * 4 + 2]; v.w = p[i4 * 4 + 3];
                *(float4*)(orow + i4 * 64 + cl * 4) = v;
            }

            // P -> Pb[ai] bf16 in chunk-XOR A-frag layout
#pragma unroll
            for (int i4 = 0; i4 < 8; ++i4) {
                unsigned b0 = __float_as_uint(p[i4 * 4 + 0]) + 0x8000u;
                unsigned b1 = __float_as_uint(p[i4 * 4 + 1]) + 0x8000u;
                unsigned b2 = __float_as_uint(p[i4 * 4 + 2]) + 0x8000u;
                unsigned b3 = __float_as_uint(p[i4 * 4 + 3]) + 0x8000u;
                uint2 pk;
                pk.x = __builtin_amdgcn_perm(b1, b0, 0x07060302u);
                pk.y = __builtin_amdgcn_perm(b3, b2, 0x07060302u);
                int h = i4 * 8 + (cl >> 1);
                *(uint2*)(Pb + ai * 8192 + row * 512 + ((h ^ (row & 7)) << 3)
                          + (cl & 1) * 4) = pk;
            }
        }
        barrier_lds();   // pair Pb visible before PV reads (LDS only)

        // ---- pair PV: each bfr load feeds 2 attrs (8 MFMAs/kc) ----------
        floatx4 acc[2][4];
#pragma unroll
        for (int ai = 0; ai < 2; ++ai)
#pragma unroll
            for (int i = 0; i < 4; ++i) acc[ai][i] = (floatx4){0.f, 0.f, 0.f, 0.f};

        for (int kc = 0; kc < 16; ++kc) {
            short8 bfr[4];
#pragma unroll
            for (int i = 0; i < 4; ++i)
                bfr[i] = *(const short8*)(sentFB +
                    (((size_t)(bb * 16 + wv * 4 + i) * 16 + kc) << 9) + lane * 8);
#pragma unroll
            for (int ai = 0; ai < 2; ++ai) {
                short8 afr = *(const short8*)(Pb + ai * 8192 + l16 * 512 +
                    (((kc * 4 + quad) ^ (l16 & 7)) << 3));
#pragma unroll
                for (int i = 0; i < 4; ++i)
                    acc[ai][i] = mfma16(afr, bfr[i], acc[ai][i]);
            }
        }
        barrier_lds();   // pair PV Pb-reads drained before Xb2 overwrites

        // ---- epilogue pair: Xb2[ai] frag layout (R17-verified):
        //   t' = a*64 + t0/8 + g, k' = (tl&7)*256 + e
#pragma unroll
        for (int ai = 0; ai < 2; ++ai) {
            float av = atr[bb * At + a0 + ph * 2 + ai];
#pragma unroll
            for (int i = 0; i < 4; ++i) {
                int W16 = wv * 4 + i;                 // e / 16
                int kcb = W16 >> 1;
                int qp  = (W16 & 1) * 2 + (l16 >> 3);
                int jp  = l16 & 7;
#pragma unroll
                for (int r = 0; r < 4; ++r) {
                    int tl = quad * 4 + r;
                    Xb2[ai * 4096 + (((tl & 7) * 8 + kcb) << 6) + qp * 16
                        + ((tl >> 3) << 3) + jp] = f2bf(av * acc[ai][i][r]);
                }
            }
        }
        barrier_lds();   // Xb2 visible before copy reads (LDS only)

        // ---- Xb2 -> XwsF frag blocks (TPT = a*4 + t0/128), rows L, L+1.
#pragma unroll
        for (int ai = 0; ai < 2; ++ai) {
            int a = a0 + ph * 2 + ai;
            int kc = tid >> 2, qp = tid & 3;
            int TPT = (a << 2) + (t0 >> 7);
            size_t base = (((size_t)(bb * 32 + TPT)) * 64 + kc) * 512;
            short8 v0 = *(const short8*)(Xb2 + ai * 4096 + (kc << 6) + qp * 16);
            short8 v1 = *(const short8*)(Xb2 + ai * 4096 + (kc << 6) + qp * 16 + 8);
            *(short8*)(XwsF + base + (qp * 16 + L) * 8)     = v0;
            *(short8*)(XwsF + base + (qp * 16 + L + 1) * 8) = v1;
        }
        barrier_lds();   // copy's LDS reads done before next pair's Pb writes
    }
}

// ---- K3: out = Xr @ W^T + bias. LDS-FREE streaming GEMM (R17-verified) ---
// 1024 blocks (16 bb x 32 TPT x 2 n-halves), XCD-swizzled bb-major to match
// the producer's L2 placement. A-frags are contiguous 1KB wave loads from
// frag-major XwsF; B-frags from Wp. No LDS, no barriers.
__global__ __launch_bounds__(256) void k_out(const unsigned short* __restrict__ XwsF,
                                             const unsigned short* __restrict__ Wp,
                                             const float* __restrict__ bias,
                                             float* __restrict__ out) {
    int hw = blockIdx.x;                    // 1024, bijective
    int logical = (hw & 7) * 128 + (hw >> 3);
    int bb  = logical >> 6;                 // 16 (2 per XCD)
    int TPT = (logical >> 1) & 31;          // 32
    int nh  = logical & 1;                  // n half
    int tid = threadIdx.x;
    int wv = tid >> 6, lane = tid & 63, quad = lane >> 4, l16 = lane & 15;

    const unsigned short* Abase = XwsF + ((size_t)(bb * 32 + TPT)) * 64 * 512 + lane * 8;
    floatx4 oacc[2];
    oacc[0] = (floatx4){0.f, 0.f, 0.f, 0.f};
    oacc[1] = (floatx4){0.f, 0.f, 0.f, 0.f};
    int nt0 = nh * 8 + wv * 2;
#pragma unroll 4
    for (int kc = 0; kc < 64; ++kc) {
        short8 afr = *(const short8*)(Abase + kc * 512);
#pragma unroll
        for (int i = 0; i < 2; ++i) {
            short8 bf = *(const short8*)(Wp +
                (((size_t)(nt0 + i) * 64 + kc) << 9) + lane * 8);
            oacc[i] = mfma16(afr, bf, oacc[i]);
        }
    }
#pragma unroll
    for (int i = 0; i < 2; ++i) {
        int n = (nt0 + i) * 16 + l16;
        float bv = bias[n];
#pragma unroll
        for (int r = 0; r < 4; ++r) {
            int tp = TPT * 16 + quad * 4 + r;
            out[((size_t)bb * Tt + tp) * Et + n] = oacc[i][r] + bv;
        }
    }
}

extern "C" void kernel_launch(void* const* d_in, const int* in_sizes, int n_in,
                              void* d_out, int out_size, void* d_ws, size_t ws_size,
                              hipStream_t stream) {
    const float* sent = (const float*)d_in[0];   // f32 (B,T,E)
    const int*   mask = (const int*)d_in[1];     // int32 (B,T)
    const float* atr  = (const float*)d_in[2];   // f32 (B,A)
    const float* W    = (const float*)d_in[3];   // f32 (E, A*E)
    const float* bias = (const float*)d_in[4];   // f32 (E)

    float* out0  = (float*)d_out;                     // 2,097,152 f32
    float* attnf = out0 + (size_t)Bt * Tt * Et;       // 33,554,432 f32

    char* ws = (char*)d_ws;
    unsigned short* sentG  = (unsigned short*)(ws);             // 4 MB
    unsigned short* sentFB = (unsigned short*)(ws + 4194304);   // 4 MB
    unsigned short* Wp     = (unsigned short*)(ws + 8388608);   // 1 MB
    unsigned short* XwsF   = (unsigned short*)(ws + 9437184);   // 32 MB frag-major
    // total 42.99 MB (== R2/R9 proven-safe footprint)

    hipLaunchKernelGGL(k_prep_sent, dim3(Tt / 32, Et / 32, Bt), dim3(256), 0, stream,
                       sent, sentG, sentFB);
    hipLaunchKernelGGL(k_prep_w, dim3(16, 8), dim3(256), 0, stream, W, Wp);
    hipLaunchKernelGGL(k_attnpv, dim3(1024), dim3(256), 0, stream,
                       sentG, sentFB, mask, atr, attnf, XwsF);
    hipLaunchKernelGGL(k_out, dim3(1024), dim3(256), 0, stream,
                       XwsF, Wp, bias, out0);
}

// Round 11
// 236.666 us; speedup vs baseline: 1.2829x; 1.2829x over previous
//
#include <hip/hip_runtime.h>
#include <hip/hip_bf16.h>

// B=16, T=512, E=256, A=8. Inputs f32 (+int32 mask), outputs f32:
//   d_out: [ output 16*512*256 | attn 128*512*512 ]
// R21 == R20 resubmit (round 10 died on infra, no signal).
// R20: R19 minus the launch_bounds footgun. R19's __launch_bounds__(256,4)
// capped VGPR at 64 -> w[32]/p[32] spilled to scratch (FETCH 5MB->109MB,
// k_attnpv 140us). With ~116 VGPR, 4 waves/SIMD fits naturally (464<=512)
// and LDS 35.3KB already allows 4 blocks/CU -- the hint was unnecessary.
// Structure (verified R19, absmax 0.015625): 2 PAIRS per block, per pair
// {2 sequential softmaxes (one p[32] live) -> pair-Pb(32KB) -> batched PV
// (bfr feeds 2 attrs) -> epilogue -> copy-out}. sentFB 512KB/block.
// Keeps: R17-verified frag-major XwsF transport + LDS-free k_out,
// bb-major XCD swizzle, lgkm-only barriers.

#define Bt 16
#define Tt 512
#define Et 256
#define At 8

typedef __attribute__((ext_vector_type(8))) short short8;   // 8 x bf16
typedef __attribute__((ext_vector_type(4))) float floatx4;

static __device__ __forceinline__ unsigned short f2bf(float x) {
    union { float f; unsigned u; } v; v.f = x;
    unsigned r = v.u + 0x7fffu + ((v.u >> 16) & 1u);  // RNE
    return (unsigned short)(r >> 16);
}

static __device__ __forceinline__ floatx4 mfma16(short8 a, short8 b, floatx4 c) {
    return __builtin_amdgcn_mfma_f32_16x16x32_bf16(a, b, c, 0, 0, 0);
}

// Barrier that waits only on LDS ops (lgkmcnt), NOT on in-flight global
// stores (vmcnt). All barriers in k_attnpv protect LDS-only data
// (S / Pb / Xb2 / msk), so lgkm-only is sufficient (audited R11/R12/R18).
static __device__ __forceinline__ void barrier_lds() {
    __builtin_amdgcn_sched_barrier(0);
    asm volatile("s_waitcnt lgkmcnt(0)" ::: "memory");
    __builtin_amdgcn_s_barrier();
    __builtin_amdgcn_sched_barrier(0);
}

// ---- prep: sentG (Gram frags, k=e) + sentFB (PV B-frags, k=s) ------------
__global__ __launch_bounds__(256) void k_prep_sent(const float* __restrict__ sent,
                                                   unsigned short* __restrict__ sentG,
                                                   unsigned short* __restrict__ sentFB) {
    int bb = blockIdx.z;
    int s0 = blockIdx.x * 32;       // 16
    int e0 = blockIdx.y * 32;       // 8
    __shared__ float tile[32][33];
    int c  = threadIdx.x & 31;
    int r4 = threadIdx.x >> 5;
    for (int i = 0; i < 4; ++i) {
        int r = r4 + 8 * i;
        tile[r][c] = sent[(bb * Tt + s0 + r) * Et + e0 + c];
    }
    __syncthreads();
    int wv = threadIdx.x >> 6, lane = threadIdx.x & 63, quad = lane >> 4, l16 = lane & 15;
    union { short8 s; unsigned short e[8]; } u;
    if (wv < 2) {
        // sentG block (bb, st = s0/16 + wv, ec = e0/32)
#pragma unroll
        for (int j = 0; j < 8; ++j) u.e[j] = f2bf(tile[wv * 16 + l16][quad * 8 + j]);
        *(short8*)(sentG + (((size_t)(bb * 32 + (s0 >> 4) + wv)) * 8 + (e0 >> 5)) * 512
                   + lane * 8) = u.s;
    } else {
        int h = wv - 2;
        // sentFB block (bb, et = e0/16 + h, sc = s0/32)
#pragma unroll
        for (int j = 0; j < 8; ++j) u.e[j] = f2bf(tile[quad * 8 + j][h * 16 + l16]);
        *(short8*)(sentFB + (((size_t)(bb * 16 + (e0 >> 4) + h)) * 16 + (s0 >> 5)) * 512
                   + lane * 8) = u.s;
    }
}

// ---- prep: Wp (B-frag-major W), verified R9. Split over 8 y-blocks. ------
__global__ __launch_bounds__(256) void k_prep_w(const float* __restrict__ W,
                                                unsigned short* __restrict__ Wp) {
    int nt = blockIdx.x;                  // 16
    int pc = blockIdx.y;                  // 8 chunks of 2 p-iterations
    int wave = threadIdx.x >> 6, lane = threadIdx.x & 63, quad = lane >> 4, l16 = lane & 15;
    const int KK = At * Et;               // 2048
    for (int p = pc * 2; p < pc * 2 + 2; ++p) {
        int kc = wave + 4 * p;            // 64
        const float* src = W + (size_t)(nt * 16 + l16) * KK + kc * 32 + quad * 8;
        union { short8 s; unsigned short e[8]; } u;
#pragma unroll
        for (int j = 0; j < 8; ++j) u.e[j] = f2bf(src[j]);
        *(short8*)(Wp + (((size_t)nt * 64 + kc) << 9) + lane * 8) = u.s;
    }
}

// ---- fused: Gram + 2x{pair softmax + pair PV + epilogue} + frag X out ----
// 1D grid, 1024 blocks. bb-major XCD-chunked swizzle: XCD k owns bb {2k,2k+1}
// (1MB sentG+sentFB working set per XCD L2). Per block: 4 attrs in 2 pairs.
__global__ __launch_bounds__(256) void k_attnpv(const unsigned short* __restrict__ sentG,
                                                const unsigned short* __restrict__ sentFB,
                                                const int* __restrict__ mask,
                                                const float* __restrict__ atr,
                                                float* __restrict__ attnf,
                                                unsigned short* __restrict__ XwsF) {
    int hw = blockIdx.x;                        // 1024, 1024%8==0 -> bijective
    int logical = (hw & 7) * 128 + (hw >> 3);
    int bb = logical >> 6;                      // 16 (slow axis: 2 per XCD)
    int z  = (logical >> 5) & 1;                // a-group 0/1
    int t0 = (logical & 31) * 16;               // 32 tiles
    int a0 = z * 4;

    // 33 KB region: phase A = S[16][516] scores; per pair: Pb[2][8192 shorts]
    // (32 KB); epilogue: Xb2[2][4096 shorts] (16 KB, aliases Pb[0]).
    __shared__ __align__(16) float Sbuf[8256];
    __shared__ float msk[512];
    __shared__ float mrowv[16];
    unsigned short* Pb  = (unsigned short*)Sbuf;
    unsigned short* Xb2 = (unsigned short*)Sbuf;

    int tid = threadIdx.x;
    for (int i = tid; i < 512; i += 256) msk[i] = (mask[bb * Tt + i] != 0) ? 1.0f : 0.0f;
    if (tid < 16) mrowv[tid] = (mask[bb * Tt + t0 + tid] != 0) ? 1.0f : 0.0f;
    barrier_lds();

    int wv = tid >> 6, lane = tid & 63, quad = lane >> 4, l16 = lane & 15;

    // ---- Gram: A and B frags both from frag-major sentG (contiguous 1KB/wave)
    const unsigned short* Gbase = sentG + ((size_t)(bb * 32 + (t0 >> 4)) * 8) * 512 + lane * 8;
    short8 af[8];
#pragma unroll
    for (int kk = 0; kk < 8; ++kk) af[kk] = *(const short8*)(Gbase + kk * 512);

#pragma unroll
    for (int i = 0; i < 8; ++i) {
        int nt = wv * 8 + i;
        const unsigned short* Bb = sentG + ((size_t)(bb * 32 + nt) * 8) * 512 + lane * 8;
        floatx4 c = {0.f, 0.f, 0.f, 0.f};
#pragma unroll
        for (int kk = 0; kk < 8; ++kk)
            c = mfma16(af[kk], *(const short8*)(Bb + kk * 512), c);
#pragma unroll
        for (int r = 0; r < 4; ++r) {
            int cidx = nt * 16 + l16;
            Sbuf[(quad * 4 + r) * 516 + cidx] = c[r] * msk[cidx] * mrowv[quad * 4 + r];
        }
    }
    barrier_lds();

    // ---- hoist masked scores to regs; one max-reduction for all attrs
    int row = tid >> 4, cl = tid & 15;
    float w[32];
    float wmax = -1e30f;
#pragma unroll
    for (int i4 = 0; i4 < 8; ++i4) {
        float4 v = *(const float4*)&Sbuf[row * 516 + i4 * 64 + cl * 4];
        w[i4 * 4 + 0] = v.x; w[i4 * 4 + 1] = v.y; w[i4 * 4 + 2] = v.z; w[i4 * 4 + 3] = v.w;
        wmax = fmaxf(wmax, fmaxf(fmaxf(v.x, v.y), fmaxf(v.z, v.w)));
    }
#pragma unroll
    for (int off = 8; off >= 1; off >>= 1) wmax = fmaxf(wmax, __shfl_xor(wmax, off, 64));
    barrier_lds();    // all S reads done before Pb overwrites the region

    int L = (t0 >> 3) & 15;                 // t'-row base within its 16-tile

    for (int ph = 0; ph < 2; ++ph) {
        // ---- pair softmax: sequential, one p[32] live at a time ---------
#pragma unroll
        for (int ai = 0; ai < 2; ++ai) {
            int a = a0 + ph * 2 + ai;
            float av = atr[bb * At + a];
            float coef = av * av * (1.0f / 16.0f);
            float mx = coef * wmax;
            float p[32];
            float sum = 0.f;
#pragma unroll
            for (int j = 0; j < 32; ++j) {
                float e = __expf(fmaf(coef, w[j], -mx));
                p[j] = e;
                sum += e;
            }
#pragma unroll
            for (int off = 8; off >= 1; off >>= 1) sum += __shfl_xor(sum, off, 64);
            float inv = 1.0f / sum;
#pragma unroll
            for (int j = 0; j < 32; ++j) p[j] *= inv;

            // attn f32 store (coalesced) -- fire-and-forget; lgkm-only
            // barriers below do NOT drain these.
            float* orow = attnf + ((size_t)(bb * At + a) * Tt + (t0 + row)) * Tt;
#pragma unroll
            for (int i4 = 0; i4 < 8; ++i4) {
                float4 v;
                v.x = p[i4 * 4 + 0]; v.y = p[i4 * 4 + 1];
                v.z = p[i4 * 4 + 2]; v.w = p[i4 * 4 + 3];
                *(float4*)(orow + i4 * 64 + cl * 4) = v;
            }

            // P -> Pb[ai] bf16 in chunk-XOR A-frag layout
#pragma unroll
            for (int i4 = 0; i4 < 8; ++i4) {
                unsigned b0 = __float_as_uint(p[i4 * 4 + 0]) + 0x8000u;
                unsigned b1 = __float_as_uint(p[i4 * 4 + 1]) + 0x8000u;
                unsigned b2 = __float_as_uint(p[i4 * 4 + 2]) + 0x8000u;
                unsigned b3 = __float_as_uint(p[i4 * 4 + 3]) + 0x8000u;
                uint2 pk;
                pk.x = __builtin_amdgcn_perm(b1, b0, 0x07060302u);
                pk.y = __builtin_amdgcn_perm(b3, b2, 0x07060302u);
                int h = i4 * 8 + (cl >> 1);
                *(uint2*)(Pb + ai * 8192 + row * 512 + ((h ^ (row & 7)) << 3)
                          + (cl & 1) * 4) = pk;
            }
        }
        barrier_lds();   // pair Pb visible before PV reads (LDS only)

        // ---- pair PV: each bfr load feeds 2 attrs (8 MFMAs/kc) ----------
        floatx4 acc[2][4];
#pragma unroll
        for (int ai = 0; ai < 2; ++ai)
#pragma unroll
            for (int i = 0; i < 4; ++i) acc[ai][i] = (floatx4){0.f, 0.f, 0.f, 0.f};

        for (int kc = 0; kc < 16; ++kc) {
            short8 bfr[4];
#pragma unroll
            for (int i = 0; i < 4; ++i)
                bfr[i] = *(const short8*)(sentFB +
                    (((size_t)(bb * 16 + wv * 4 + i) * 16 + kc) << 9) + lane * 8);
#pragma unroll
            for (int ai = 0; ai < 2; ++ai) {
                short8 afr = *(const short8*)(Pb + ai * 8192 + l16 * 512 +
                    (((kc * 4 + quad) ^ (l16 & 7)) << 3));
#pragma unroll
                for (int i = 0; i < 4; ++i)
                    acc[ai][i] = mfma16(afr, bfr[i], acc[ai][i]);
            }
        }
        barrier_lds();   // pair PV Pb-reads drained before Xb2 overwrites

        // ---- epilogue pair: Xb2[ai] frag layout (R17-verified):
        //   t' = a*64 + t0/8 + g, k' = (tl&7)*256 + e
#pragma unroll
        for (int ai = 0; ai < 2; ++ai) {
            float av = atr[bb * At + a0 + ph * 2 + ai];
#pragma unroll
            for (int i = 0; i < 4; ++i) {
                int W16 = wv * 4 + i;                 // e / 16
                int kcb = W16 >> 1;
                int qp  = (W16 & 1) * 2 + (l16 >> 3);
                int jp  = l16 & 7;
#pragma unroll
                for (int r = 0; r < 4; ++r) {
                    int tl = quad * 4 + r;
                    Xb2[ai * 4096 + (((tl & 7) * 8 + kcb) << 6) + qp * 16
                        + ((tl >> 3) << 3) + jp] = f2bf(av * acc[ai][i][r]);
                }
            }
        }
        barrier_lds();   // Xb2 visible before copy reads (LDS only)

        // ---- Xb2 -> XwsF frag blocks (TPT = a*4 + t0/128), rows L, L+1.
#pragma unroll
        for (int ai = 0; ai < 2; ++ai) {
            int a = a0 + ph * 2 + ai;
            int kc = tid >> 2, qp = tid & 3;
            int TPT = (a << 2) + (t0 >> 7);
            size_t base = (((size_t)(bb * 32 + TPT)) * 64 + kc) * 512;
            short8 v0 = *(const short8*)(Xb2 + ai * 4096 + (kc << 6) + qp * 16);
            short8 v1 = *(const short8*)(Xb2 + ai * 4096 + (kc << 6) + qp * 16 + 8);
            *(short8*)(XwsF + base + (qp * 16 + L) * 8)     = v0;
            *(short8*)(XwsF + base + (qp * 16 + L + 1) * 8) = v1;
        }
        barrier_lds();   // copy's LDS reads done before next pair's Pb writes
    }
}

// ---- K3: out = Xr @ W^T + bias. LDS-FREE streaming GEMM (R17-verified) ---
// 1024 blocks (16 bb x 32 TPT x 2 n-halves), XCD-swizzled bb-major to match
// the producer's L2 placement. A-frags are contiguous 1KB wave loads from
// frag-major XwsF; B-frags from Wp. No LDS, no barriers.
__global__ __launch_bounds__(256) void k_out(const unsigned short* __restrict__ XwsF,
                                             const unsigned short* __restrict__ Wp,
                                             const float* __restrict__ bias,
                                             float* __restrict__ out) {
    int hw = blockIdx.x;                    // 1024, bijective
    int logical = (hw & 7) * 128 + (hw >> 3);
    int bb  = logical >> 6;                 // 16 (2 per XCD)
    int TPT = (logical >> 1) & 31;          // 32
    int nh  = logical & 1;                  // n half
    int tid = threadIdx.x;
    int wv = tid >> 6, lane = tid & 63, quad = lane >> 4, l16 = lane & 15;

    const unsigned short* Abase = XwsF + ((size_t)(bb * 32 + TPT)) * 64 * 512 + lane * 8;
    floatx4 oacc[2];
    oacc[0] = (floatx4){0.f, 0.f, 0.f, 0.f};
    oacc[1] = (floatx4){0.f, 0.f, 0.f, 0.f};
    int nt0 = nh * 8 + wv * 2;
#pragma unroll 4
    for (int kc = 0; kc < 64; ++kc) {
        short8 afr = *(const short8*)(Abase + kc * 512);
#pragma unroll
        for (int i = 0; i < 2; ++i) {
            short8 bf = *(const short8*)(Wp +
                (((size_t)(nt0 + i) * 64 + kc) << 9) + lane * 8);
            oacc[i] = mfma16(afr, bf, oacc[i]);
        }
    }
#pragma unroll
    for (int i = 0; i < 2; ++i) {
        int n = (nt0 + i) * 16 + l16;
        float bv = bias[n];
#pragma unroll
        for (int r = 0; r < 4; ++r) {
            int tp = TPT * 16 + quad * 4 + r;
            out[((size_t)bb * Tt + tp) * Et + n] = oacc[i][r] + bv;
        }
    }
}

extern "C" void kernel_launch(void* const* d_in, const int* in_sizes, int n_in,
                              void* d_out, int out_size, void* d_ws, size_t ws_size,
                              hipStream_t stream) {
    const float* sent = (const float*)d_in[0];   // f32 (B,T,E)
    const int*   mask = (const int*)d_in[1];     // int32 (B,T)
    const float* atr  = (const float*)d_in[2];   // f32 (B,A)
    const float* W    = (const float*)d_in[3];   // f32 (E, A*E)
    const float* bias = (const float*)d_in[4];   // f32 (E)

    float* out0  = (float*)d_out;                     // 2,097,152 f32
    float* attnf = out0 + (size_t)Bt * Tt * Et;       // 33,554,432 f32

    char* ws = (char*)d_ws;
    unsigned short* sentG  = (unsigned short*)(ws);             // 4 MB
    unsigned short* sentFB = (unsigned short*)(ws + 4194304);   // 4 MB
    unsigned short* Wp     = (unsigned short*)(ws + 8388608);   // 1 MB
    unsigned short* XwsF   = (unsigned short*)(ws + 9437184);   // 32 MB frag-major
    // total 42.99 MB (== R2/R9 proven-safe footprint)

    hipLaunchKernelGGL(k_prep_sent, dim3(Tt / 32, Et / 32, Bt), dim3(256), 0, stream,
                       sent, sentG, sentFB);
    hipLaunchKernelGGL(k_prep_w, dim3(16, 8), dim3(256), 0, stream, W, Wp);
    hipLaunchKernelGGL(k_attnpv, dim3(1024), dim3(256), 0, stream,
                       sentG, sentFB, mask, atr, attnf, XwsF);
    hipLaunchKernelGGL(k_out, dim3(1024), dim3(256), 0, stream,
                       XwsF, Wp, bias, out0);
}

// Round 12
// 217.942 us; speedup vs baseline: 1.3931x; 1.0859x over previous
//
#include <hip/hip_runtime.h>
#include <hip/hip_bf16.h>

// B=16, T=512, E=256, A=8. Inputs f32 (+int32 mask), outputs f32:
//   d_out: [ output 16*512*256 | attn 128*512*512 ]
// R22: k_attnpv = R18 exact (session best, 219.1us: z=2, all-4 softmax
// first so w[32] dies before PV, kc-outer batched PV acc[4][4], 67.6KB LDS).
// R19/R21 pair variants refuted: w-liveness across pairs -> 136 VGPR.
// k_out retiled Mt=2 x Nt=2 per wave (block = 2 TPT x 128 cols, 512 blocks):
// loads/MFMA 1.5 -> 1.0 (L2 768->512MB). Per-element kc order unchanged ->
// bitwise-identical. Keeps R17 frag-major XwsF transport, bb-major XCD
// swizzle, lgkm-only barriers.

#define Bt 16
#define Tt 512
#define Et 256
#define At 8

typedef __attribute__((ext_vector_type(8))) short short8;   // 8 x bf16
typedef __attribute__((ext_vector_type(4))) float floatx4;

static __device__ __forceinline__ unsigned short f2bf(float x) {
    union { float f; unsigned u; } v; v.f = x;
    unsigned r = v.u + 0x7fffu + ((v.u >> 16) & 1u);  // RNE
    return (unsigned short)(r >> 16);
}

static __device__ __forceinline__ floatx4 mfma16(short8 a, short8 b, floatx4 c) {
    return __builtin_amdgcn_mfma_f32_16x16x32_bf16(a, b, c, 0, 0, 0);
}

// Barrier that waits only on LDS ops (lgkmcnt), NOT on in-flight global
// stores (vmcnt). All barriers in k_attnpv protect LDS-only data
// (S / Pb / Xb2 / msk), so lgkm-only is sufficient (audited R11/R12/R18).
static __device__ __forceinline__ void barrier_lds() {
    __builtin_amdgcn_sched_barrier(0);
    asm volatile("s_waitcnt lgkmcnt(0)" ::: "memory");
    __builtin_amdgcn_s_barrier();
    __builtin_amdgcn_sched_barrier(0);
}

// ---- prep: sentG (Gram frags, k=e) + sentFB (PV B-frags, k=s) ------------
__global__ __launch_bounds__(256) void k_prep_sent(const float* __restrict__ sent,
                                                   unsigned short* __restrict__ sentG,
                                                   unsigned short* __restrict__ sentFB) {
    int bb = blockIdx.z;
    int s0 = blockIdx.x * 32;       // 16
    int e0 = blockIdx.y * 32;       // 8
    __shared__ float tile[32][33];
    int c  = threadIdx.x & 31;
    int r4 = threadIdx.x >> 5;
    for (int i = 0; i < 4; ++i) {
        int r = r4 + 8 * i;
        tile[r][c] = sent[(bb * Tt + s0 + r) * Et + e0 + c];
    }
    __syncthreads();
    int wv = threadIdx.x >> 6, lane = threadIdx.x & 63, quad = lane >> 4, l16 = lane & 15;
    union { short8 s; unsigned short e[8]; } u;
    if (wv < 2) {
        // sentG block (bb, st = s0/16 + wv, ec = e0/32)
#pragma unroll
        for (int j = 0; j < 8; ++j) u.e[j] = f2bf(tile[wv * 16 + l16][quad * 8 + j]);
        *(short8*)(sentG + (((size_t)(bb * 32 + (s0 >> 4) + wv)) * 8 + (e0 >> 5)) * 512
                   + lane * 8) = u.s;
    } else {
        int h = wv - 2;
        // sentFB block (bb, et = e0/16 + h, sc = s0/32)
#pragma unroll
        for (int j = 0; j < 8; ++j) u.e[j] = f2bf(tile[quad * 8 + j][h * 16 + l16]);
        *(short8*)(sentFB + (((size_t)(bb * 16 + (e0 >> 4) + h)) * 16 + (s0 >> 5)) * 512
                   + lane * 8) = u.s;
    }
}

// ---- prep: Wp (B-frag-major W), verified R9. Split over 8 y-blocks. ------
__global__ __launch_bounds__(256) void k_prep_w(const float* __restrict__ W,
                                                unsigned short* __restrict__ Wp) {
    int nt = blockIdx.x;                  // 16
    int pc = blockIdx.y;                  // 8 chunks of 2 p-iterations
    int wave = threadIdx.x >> 6, lane = threadIdx.x & 63, quad = lane >> 4, l16 = lane & 15;
    const int KK = At * Et;               // 2048
    for (int p = pc * 2; p < pc * 2 + 2; ++p) {
        int kc = wave + 4 * p;            // 64
        const float* src = W + (size_t)(nt * 16 + l16) * KK + kc * 32 + quad * 8;
        union { short8 s; unsigned short e[8]; } u;
#pragma unroll
        for (int j = 0; j < 8; ++j) u.e[j] = f2bf(src[j]);
        *(short8*)(Wp + (((size_t)nt * 64 + kc) << 9) + lane * 8) = u.s;
    }
}

// ---- fused: Gram + 4x softmax + batched PV + frag-major X out (R18) ------
// 1D grid, 1024 blocks. bb-major XCD-chunked swizzle: XCD k owns bb {2k,2k+1}
// (1MB sentG+sentFB working set per XCD L2). Per block: 4 attrs (z*4..+4).
__global__ __launch_bounds__(256) void k_attnpv(const unsigned short* __restrict__ sentG,
                                                const unsigned short* __restrict__ sentFB,
                                                const int* __restrict__ mask,
                                                const float* __restrict__ atr,
                                                float* __restrict__ attnf,
                                                unsigned short* __restrict__ XwsF) {
    int hw = blockIdx.x;                        // 1024, 1024%8==0 -> bijective
    int logical = (hw & 7) * 128 + (hw >> 3);
    int bb = logical >> 6;                      // 16 (slow axis: 2 per XCD)
    int z  = (logical >> 5) & 1;                // a-group 0/1
    int t0 = (logical & 31) * 16;               // 32 tiles
    int a0 = z * 4;

    // 64 KB region: phase A = S[16][516] scores; phase B = Pb[4][8192] bf16;
    // phase C = Xb2[4][4096] bf16 (aliases Pb[0..1] after barrier).
    __shared__ __align__(16) float Sbuf[16384];
    __shared__ float msk[512];
    __shared__ float mrowv[16];
    unsigned short* Pb  = (unsigned short*)Sbuf;
    unsigned short* Xb2 = (unsigned short*)Sbuf;

    int tid = threadIdx.x;
    for (int i = tid; i < 512; i += 256) msk[i] = (mask[bb * Tt + i] != 0) ? 1.0f : 0.0f;
    if (tid < 16) mrowv[tid] = (mask[bb * Tt + t0 + tid] != 0) ? 1.0f : 0.0f;
    barrier_lds();

    int wv = tid >> 6, lane = tid & 63, quad = lane >> 4, l16 = lane & 15;

    // ---- Gram: A and B frags both from frag-major sentG (contiguous 1KB/wave)
    const unsigned short* Gbase = sentG + ((size_t)(bb * 32 + (t0 >> 4)) * 8) * 512 + lane * 8;
    short8 af[8];
#pragma unroll
    for (int kk = 0; kk < 8; ++kk) af[kk] = *(const short8*)(Gbase + kk * 512);

#pragma unroll
    for (int i = 0; i < 8; ++i) {
        int nt = wv * 8 + i;
        const unsigned short* Bb = sentG + ((size_t)(bb * 32 + nt) * 8) * 512 + lane * 8;
        floatx4 c = {0.f, 0.f, 0.f, 0.f};
#pragma unroll
        for (int kk = 0; kk < 8; ++kk)
            c = mfma16(af[kk], *(const short8*)(Bb + kk * 512), c);
#pragma unroll
        for (int r = 0; r < 4; ++r) {
            int cidx = nt * 16 + l16;
            Sbuf[(quad * 4 + r) * 516 + cidx] = c[r] * msk[cidx] * mrowv[quad * 4 + r];
        }
    }
    barrier_lds();

    // ---- hoist masked scores to regs; one max-reduction for all attrs
    int row = tid >> 4, cl = tid & 15;
    float w[32];
    float wmax = -1e30f;
#pragma unroll
    for (int i4 = 0; i4 < 8; ++i4) {
        float4 v = *(const float4*)&Sbuf[row * 516 + i4 * 64 + cl * 4];
        w[i4 * 4 + 0] = v.x; w[i4 * 4 + 1] = v.y; w[i4 * 4 + 2] = v.z; w[i4 * 4 + 3] = v.w;
        wmax = fmaxf(wmax, fmaxf(fmaxf(v.x, v.y), fmaxf(v.z, v.w)));
    }
#pragma unroll
    for (int off = 8; off >= 1; off >>= 1) wmax = fmaxf(wmax, __shfl_xor(wmax, off, 64));
    barrier_lds();    // all S reads done before Pb overwrites the region

    int L = (t0 >> 3) & 15;                 // t'-row base within its 16-tile

    // ---- phase 1: all 4 softmaxes -> attn stores + Pb[al] (one p[] live)
#pragma unroll
    for (int al = 0; al < 4; ++al) {
        int a = a0 + al;
        float av = atr[bb * At + a];
        float coef = av * av * (1.0f / 16.0f);
        float mx = coef * wmax;
        float p[32];
        float sum = 0.f;
#pragma unroll
        for (int j = 0; j < 32; ++j) {
            float e = __expf(fmaf(coef, w[j], -mx));
            p[j] = e;
            sum += e;
        }
#pragma unroll
        for (int off = 8; off >= 1; off >>= 1) sum += __shfl_xor(sum, off, 64);
        float inv = 1.0f / sum;
#pragma unroll
        for (int j = 0; j < 32; ++j) p[j] *= inv;

        // attn f32 store (coalesced) -- fire-and-forget; the lgkm-only
        // barriers below do NOT drain these.
        float* orow = attnf + ((size_t)(bb * At + a) * Tt + (t0 + row)) * Tt;
#pragma unroll
        for (int i4 = 0; i4 < 8; ++i4) {
            float4 v;
            v.x = p[i4 * 4 + 0]; v.y = p[i4 * 4 + 1];
            v.z = p[i4 * 4 + 2]; v.w = p[i4 * 4 + 3];
            *(float4*)(orow + i4 * 64 + cl * 4) = v;
        }

        // P -> Pb[al] bf16 in chunk-XOR A-frag layout
#pragma unroll
        for (int i4 = 0; i4 < 8; ++i4) {
            unsigned b0 = __float_as_uint(p[i4 * 4 + 0]) + 0x8000u;
            unsigned b1 = __float_as_uint(p[i4 * 4 + 1]) + 0x8000u;
            unsigned b2 = __float_as_uint(p[i4 * 4 + 2]) + 0x8000u;
            unsigned b3 = __float_as_uint(p[i4 * 4 + 3]) + 0x8000u;
            uint2 pk;
            pk.x = __builtin_amdgcn_perm(b1, b0, 0x07060302u);
            pk.y = __builtin_amdgcn_perm(b3, b2, 0x07060302u);
            int h = i4 * 8 + (cl >> 1);
            *(uint2*)(Pb + al * 8192 + row * 512 + ((h ^ (row & 7)) << 3)
                      + (cl & 1) * 4) = pk;
        }
    }
    barrier_lds();   // all Pb visible before PV reads (LDS only)

    // ---- phase 2: batched PV -- each bfr load feeds 4 attrs (16 MFMAs/kc)
    floatx4 acc[4][4];
#pragma unroll
    for (int al = 0; al < 4; ++al)
#pragma unroll
        for (int i = 0; i < 4; ++i) acc[al][i] = (floatx4){0.f, 0.f, 0.f, 0.f};

    for (int kc = 0; kc < 16; ++kc) {
        short8 bfr[4];
#pragma unroll
        for (int i = 0; i < 4; ++i)
            bfr[i] = *(const short8*)(sentFB +
                (((size_t)(bb * 16 + wv * 4 + i) * 16 + kc) << 9) + lane * 8);
#pragma unroll
        for (int al = 0; al < 4; ++al) {
            short8 afr = *(const short8*)(Pb + al * 8192 + l16 * 512 +
                (((kc * 4 + quad) ^ (l16 & 7)) << 3));
#pragma unroll
            for (int i = 0; i < 4; ++i)
                acc[al][i] = mfma16(afr, bfr[i], acc[al][i]);
        }
    }
    barrier_lds();   // all PV Pb-reads drained before Xb2 overwrites region

    // ---- phase 3: epilogue x4 -- Xb2[al] frag layout (R17-verified):
    //   t' = a*64 + t0/8 + g, k' = (tl&7)*256 + e
#pragma unroll
    for (int al = 0; al < 4; ++al) {
        float av = atr[bb * At + a0 + al];
#pragma unroll
        for (int i = 0; i < 4; ++i) {
            int W16 = wv * 4 + i;                 // e / 16
            int kcb = W16 >> 1;
            int qp  = (W16 & 1) * 2 + (l16 >> 3);
            int jp  = l16 & 7;
#pragma unroll
            for (int r = 0; r < 4; ++r) {
                int tl = quad * 4 + r;
                Xb2[al * 4096 + (((tl & 7) * 8 + kcb) << 6) + qp * 16
                    + ((tl >> 3) << 3) + jp] = f2bf(av * acc[al][i][r]);
            }
        }
    }
    barrier_lds();   // Xb2 visible before copy reads (LDS only)

    // ---- Xb2 -> XwsF frag blocks (TPT = a*4 + t0/128), rows L, L+1.
#pragma unroll
    for (int al = 0; al < 4; ++al) {
        int a = a0 + al;
        int kc = tid >> 2, qp = tid & 3;
        int TPT = (a << 2) + (t0 >> 7);
        size_t base = (((size_t)(bb * 32 + TPT)) * 64 + kc) * 512;
        short8 v0 = *(const short8*)(Xb2 + al * 4096 + (kc << 6) + qp * 16);
        short8 v1 = *(const short8*)(Xb2 + al * 4096 + (kc << 6) + qp * 16 + 8);
        *(short8*)(XwsF + base + (qp * 16 + L) * 8)     = v0;
        *(short8*)(XwsF + base + (qp * 16 + L + 1) * 8) = v1;
    }
}

// ---- K3: out = Xr @ W^T + bias. LDS-free streaming GEMM, Mt=2 x Nt=2 -----
// 512 blocks (16 bb x 16 TPT-pairs x 2 n-halves), bb-major XCD swizzle.
// Each wave: 2 TPT rows-tiles x 2 nt col-tiles; every A-frag and B-frag
// load feeds 2 MFMAs (loads/MFMA 1.0 vs R17's 1.5; L2 768->512MB).
// Per-output-element kc accumulation order unchanged -> bitwise-identical.
__global__ __launch_bounds__(256) void k_out(const unsigned short* __restrict__ XwsF,
                                             const unsigned short* __restrict__ Wp,
                                             const float* __restrict__ bias,
                                             float* __restrict__ out) {
    int hw = blockIdx.x;                    // 512, 512%8==0 -> bijective
    int logical = (hw & 7) * 64 + (hw >> 3);
    int bb   = logical >> 5;                // 16 (2 per XCD)
    int TPT0 = ((logical >> 1) & 15) * 2;   // 0,2,..,30
    int nh   = logical & 1;                 // n half
    int tid = threadIdx.x;
    int wv = tid >> 6, lane = tid & 63, quad = lane >> 4, l16 = lane & 15;

    const unsigned short* A0 = XwsF + ((size_t)(bb * 32 + TPT0)) * 64 * 512 + lane * 8;
    const unsigned short* A1 = A0 + 64 * 512;
    floatx4 oacc[2][2];
#pragma unroll
    for (int m = 0; m < 2; ++m)
#pragma unroll
        for (int i = 0; i < 2; ++i) oacc[m][i] = (floatx4){0.f, 0.f, 0.f, 0.f};
    int nt0 = nh * 8 + wv * 2;
#pragma unroll 4
    for (int kc = 0; kc < 64; ++kc) {
        short8 a0 = *(const short8*)(A0 + kc * 512);
        short8 a1 = *(const short8*)(A1 + kc * 512);
#pragma unroll
        for (int i = 0; i < 2; ++i) {
            short8 bf = *(const short8*)(Wp +
                (((size_t)(nt0 + i) * 64 + kc) << 9) + lane * 8);
            oacc[0][i] = mfma16(a0, bf, oacc[0][i]);
            oacc[1][i] = mfma16(a1, bf, oacc[1][i]);
        }
    }
#pragma unroll
    for (int m = 0; m < 2; ++m) {
#pragma unroll
        for (int i = 0; i < 2; ++i) {
            int n = (nt0 + i) * 16 + l16;
            float bv = bias[n];
#pragma unroll
            for (int r = 0; r < 4; ++r) {
                int tp = (TPT0 + m) * 16 + quad * 4 + r;
                out[((size_t)bb * Tt + tp) * Et + n] = oacc[m][i][r] + bv;
            }
        }
    }
}

extern "C" void kernel_launch(void* const* d_in, const int* in_sizes, int n_in,
                              void* d_out, int out_size, void* d_ws, size_t ws_size,
                              hipStream_t stream) {
    const float* sent = (const float*)d_in[0];   // f32 (B,T,E)
    const int*   mask = (const int*)d_in[1];     // int32 (B,T)
    const float* atr  = (const float*)d_in[2];   // f32 (B,A)
    const float* W    = (const float*)d_in[3];   // f32 (E, A*E)
    const float* bias = (const float*)d_in[4];   // f32 (E)

    float* out0  = (float*)d_out;                     // 2,097,152 f32
    float* attnf = out0 + (size_t)Bt * Tt * Et;       // 33,554,432 f32

    char* ws = (char*)d_ws;
    unsigned short* sentG  = (unsigned short*)(ws);             // 4 MB
    unsigned short* sentFB = (unsigned short*)(ws + 4194304);   // 4 MB
    unsigned short* Wp     = (unsigned short*)(ws + 8388608);   // 1 MB
    unsigned short* XwsF   = (unsigned short*)(ws + 9437184);   // 32 MB frag-major
    // total 42.99 MB (== R2/R9 proven-safe footprint)

    hipLaunchKernelGGL(k_prep_sent, dim3(Tt / 32, Et / 32, Bt), dim3(256), 0, stream,
                       sent, sentG, sentFB);
    hipLaunchKernelGGL(k_prep_w, dim3(16, 8), dim3(256), 0, stream, W, Wp);
    hipLaunchKernelGGL(k_attnpv, dim3(1024), dim3(256), 0, stream,
                       sentG, sentFB, mask, atr, attnf, XwsF);
    hipLaunchKernelGGL(k_out, dim3(512), dim3(256), 0, stream,
                       XwsF, Wp, bias, out0);
}

// Round 13
// 209.727 us; speedup vs baseline: 1.4477x; 1.0392x over previous
//
#include <hip/hip_runtime.h>
#include <hip/hip_bf16.h>

// B=16, T=512, E=256, A=8. Inputs f32 (+int32 mask), outputs f32:
//   d_out: [ output 16*512*256 | attn 128*512*512 ]
// R23: R22 (best, 217.9us) with k_attnpv widened to 512 threads (8 waves).
// k_attnpv is latency-bound at 8 waves/CU (2 blk x 4 waves, 25% occ, all
// utils low). 512-thr keeps the R18 phase structure + 67.6KB LDS but gives
// 2 blk x 8 waves = 16 waves/CU (50%) and halves per-thread serial work
// (w[16]/p[16], Gram 32 MFMA/wave, PV acc[4][2]). All traffic, LDS frag
// layouts, and kc accumulation order unchanged -> bitwise-identical output.
// Re-derived for 512thr: softmax row=tid>>5 cl=tid&31 (5-step xor reduce),
// Pb h=i4*16+(cl>>1), PV et=wv*2+i, epilogue W16=wv*2+i, copy kc=tid>>3.
// k_out = R22's Mt=2xNt=2 retile (banked). No launch_bounds min-waves
// (R19 lesson: forcing occupancy spills).

#define Bt 16
#define Tt 512
#define Et 256
#define At 8

typedef __attribute__((ext_vector_type(8))) short short8;   // 8 x bf16
typedef __attribute__((ext_vector_type(4))) float floatx4;

static __device__ __forceinline__ unsigned short f2bf(float x) {
    union { float f; unsigned u; } v; v.f = x;
    unsigned r = v.u + 0x7fffu + ((v.u >> 16) & 1u);  // RNE
    return (unsigned short)(r >> 16);
}

static __device__ __forceinline__ floatx4 mfma16(short8 a, short8 b, floatx4 c) {
    return __builtin_amdgcn_mfma_f32_16x16x32_bf16(a, b, c, 0, 0, 0);
}

// Barrier that waits only on LDS ops (lgkmcnt), NOT on in-flight global
// stores (vmcnt). All barriers in k_attnpv protect LDS-only data
// (S / Pb / Xb2 / msk), so lgkm-only is sufficient (audited R11/R12/R18).
static __device__ __forceinline__ void barrier_lds() {
    __builtin_amdgcn_sched_barrier(0);
    asm volatile("s_waitcnt lgkmcnt(0)" ::: "memory");
    __builtin_amdgcn_s_barrier();
    __builtin_amdgcn_sched_barrier(0);
}

// ---- prep: sentG (Gram frags, k=e) + sentFB (PV B-frags, k=s) ------------
__global__ __launch_bounds__(256) void k_prep_sent(const float* __restrict__ sent,
                                                   unsigned short* __restrict__ sentG,
                                                   unsigned short* __restrict__ sentFB) {
    int bb = blockIdx.z;
    int s0 = blockIdx.x * 32;       // 16
    int e0 = blockIdx.y * 32;       // 8
    __shared__ float tile[32][33];
    int c  = threadIdx.x & 31;
    int r4 = threadIdx.x >> 5;
    for (int i = 0; i < 4; ++i) {
        int r = r4 + 8 * i;
        tile[r][c] = sent[(bb * Tt + s0 + r) * Et + e0 + c];
    }
    __syncthreads();
    int wv = threadIdx.x >> 6, lane = threadIdx.x & 63, quad = lane >> 4, l16 = lane & 15;
    union { short8 s; unsigned short e[8]; } u;
    if (wv < 2) {
        // sentG block (bb, st = s0/16 + wv, ec = e0/32)
#pragma unroll
        for (int j = 0; j < 8; ++j) u.e[j] = f2bf(tile[wv * 16 + l16][quad * 8 + j]);
        *(short8*)(sentG + (((size_t)(bb * 32 + (s0 >> 4) + wv)) * 8 + (e0 >> 5)) * 512
                   + lane * 8) = u.s;
    } else {
        int h = wv - 2;
        // sentFB block (bb, et = e0/16 + h, sc = s0/32)
#pragma unroll
        for (int j = 0; j < 8; ++j) u.e[j] = f2bf(tile[quad * 8 + j][h * 16 + l16]);
        *(short8*)(sentFB + (((size_t)(bb * 16 + (e0 >> 4) + h)) * 16 + (s0 >> 5)) * 512
                   + lane * 8) = u.s;
    }
}

// ---- prep: Wp (B-frag-major W), verified R9. Split over 8 y-blocks. ------
__global__ __launch_bounds__(256) void k_prep_w(const float* __restrict__ W,
                                                unsigned short* __restrict__ Wp) {
    int nt = blockIdx.x;                  // 16
    int pc = blockIdx.y;                  // 8 chunks of 2 p-iterations
    int wave = threadIdx.x >> 6, lane = threadIdx.x & 63, quad = lane >> 4, l16 = lane & 15;
    const int KK = At * Et;               // 2048
    for (int p = pc * 2; p < pc * 2 + 2; ++p) {
        int kc = wave + 4 * p;            // 64
        const float* src = W + (size_t)(nt * 16 + l16) * KK + kc * 32 + quad * 8;
        union { short8 s; unsigned short e[8]; } u;
#pragma unroll
        for (int j = 0; j < 8; ++j) u.e[j] = f2bf(src[j]);
        *(short8*)(Wp + (((size_t)nt * 64 + kc) << 9) + lane * 8) = u.s;
    }
}

// ---- fused: Gram + 4x softmax + batched PV + frag-major X out ------------
// 512 THREADS (8 waves). 1D grid, 1024 blocks. bb-major XCD-chunked swizzle:
// XCD k owns bb {2k,2k+1}. Per block: 4 attrs (z*4..+4), R18 phase order.
__global__ __launch_bounds__(512) void k_attnpv(const unsigned short* __restrict__ sentG,
                                                const unsigned short* __restrict__ sentFB,
                                                const int* __restrict__ mask,
                                                const float* __restrict__ atr,
                                                float* __restrict__ attnf,
                                                unsigned short* __restrict__ XwsF) {
    int hw = blockIdx.x;                        // 1024, 1024%8==0 -> bijective
    int logical = (hw & 7) * 128 + (hw >> 3);
    int bb = logical >> 6;                      // 16 (slow axis: 2 per XCD)
    int z  = (logical >> 5) & 1;                // a-group 0/1
    int t0 = (logical & 31) * 16;               // 32 tiles
    int a0 = z * 4;

    // 64 KB region: phase A = S[16][516] scores; phase B = Pb[4][8192] bf16;
    // phase C = Xb2[4][4096] bf16 (aliases Pb[0..1] after barrier).
    __shared__ __align__(16) float Sbuf[16384];
    __shared__ float msk[512];
    __shared__ float mrowv[16];
    unsigned short* Pb  = (unsigned short*)Sbuf;
    unsigned short* Xb2 = (unsigned short*)Sbuf;

    int tid = threadIdx.x;
    msk[tid] = (mask[bb * Tt + tid] != 0) ? 1.0f : 0.0f;
    if (tid < 16) mrowv[tid] = (mask[bb * Tt + t0 + tid] != 0) ? 1.0f : 0.0f;
    barrier_lds();

    int wv = tid >> 6, lane = tid & 63, quad = lane >> 4, l16 = lane & 15;

    // ---- Gram: A and B frags both from frag-major sentG (contiguous 1KB/wave)
    // 8 waves x 4 nt-tiles each = 32 nt-tiles.
    const unsigned short* Gbase = sentG + ((size_t)(bb * 32 + (t0 >> 4)) * 8) * 512 + lane * 8;
    short8 af[8];
#pragma unroll
    for (int kk = 0; kk < 8; ++kk) af[kk] = *(const short8*)(Gbase + kk * 512);

#pragma unroll
    for (int i = 0; i < 4; ++i) {
        int nt = wv * 4 + i;
        const unsigned short* Bb = sentG + ((size_t)(bb * 32 + nt) * 8) * 512 + lane * 8;
        floatx4 c = {0.f, 0.f, 0.f, 0.f};
#pragma unroll
        for (int kk = 0; kk < 8; ++kk)
            c = mfma16(af[kk], *(const short8*)(Bb + kk * 512), c);
#pragma unroll
        for (int r = 0; r < 4; ++r) {
            int cidx = nt * 16 + l16;
            Sbuf[(quad * 4 + r) * 516 + cidx] = c[r] * msk[cidx] * mrowv[quad * 4 + r];
        }
    }
    barrier_lds();

    // ---- hoist masked scores to regs; one max-reduction for all attrs.
    // 512 thr: row = tid>>5 (16 rows), cl = tid&31, 16 elems/thread.
    int row = tid >> 5, cl = tid & 31;
    float w[16];
    float wmax = -1e30f;
#pragma unroll
    for (int i4 = 0; i4 < 4; ++i4) {
        float4 v = *(const float4*)&Sbuf[row * 516 + i4 * 128 + cl * 4];
        w[i4 * 4 + 0] = v.x; w[i4 * 4 + 1] = v.y; w[i4 * 4 + 2] = v.z; w[i4 * 4 + 3] = v.w;
        wmax = fmaxf(wmax, fmaxf(fmaxf(v.x, v.y), fmaxf(v.z, v.w)));
    }
    // row group = 32 contiguous lanes, 32-aligned -> xor offsets 16..1 stay inside
#pragma unroll
    for (int off = 16; off >= 1; off >>= 1) wmax = fmaxf(wmax, __shfl_xor(wmax, off, 64));
    barrier_lds();    // all S reads done before Pb overwrites the region

    int L = (t0 >> 3) & 15;                 // t'-row base within its 16-tile

    // ---- phase 1: all 4 softmaxes -> attn stores + Pb[al] (one p[] live)
#pragma unroll
    for (int al = 0; al < 4; ++al) {
        int a = a0 + al;
        float av = atr[bb * At + a];
        float coef = av * av * (1.0f / 16.0f);
        float mx = coef * wmax;
        float p[16];
        float sum = 0.f;
#pragma unroll
        for (int j = 0; j < 16; ++j) {
            float e = __expf(fmaf(coef, w[j], -mx));
            p[j] = e;
            sum += e;
        }
#pragma unroll
        for (int off = 16; off >= 1; off >>= 1) sum += __shfl_xor(sum, off, 64);
        float inv = 1.0f / sum;
#pragma unroll
        for (int j = 0; j < 16; ++j) p[j] *= inv;

        // attn f32 store (coalesced) -- fire-and-forget; the lgkm-only
        // barriers below do NOT drain these.
        float* orow = attnf + ((size_t)(bb * At + a) * Tt + (t0 + row)) * Tt;
#pragma unroll
        for (int i4 = 0; i4 < 4; ++i4) {
            float4 v;
            v.x = p[i4 * 4 + 0]; v.y = p[i4 * 4 + 1];
            v.z = p[i4 * 4 + 2]; v.w = p[i4 * 4 + 3];
            *(float4*)(orow + i4 * 128 + cl * 4) = v;
        }

        // P -> Pb[al] bf16 in chunk-XOR A-frag layout.
        // col c = i4*128 + cl*4 + j -> h = i4*16 + (cl>>1), pos = (cl&1)*4 + j
#pragma unroll
        for (int i4 = 0; i4 < 4; ++i4) {
            unsigned b0 = __float_as_uint(p[i4 * 4 + 0]) + 0x8000u;
            unsigned b1 = __float_as_uint(p[i4 * 4 + 1]) + 0x8000u;
            unsigned b2 = __float_as_uint(p[i4 * 4 + 2]) + 0x8000u;
            unsigned b3 = __float_as_uint(p[i4 * 4 + 3]) + 0x8000u;
            uint2 pk;
            pk.x = __builtin_amdgcn_perm(b1, b0, 0x07060302u);
            pk.y = __builtin_amdgcn_perm(b3, b2, 0x07060302u);
            int h = i4 * 16 + (cl >> 1);
            *(uint2*)(Pb + al * 8192 + row * 512 + ((h ^ (row & 7)) << 3)
                      + (cl & 1) * 4) = pk;
        }
    }
    barrier_lds();   // all Pb visible before PV reads (LDS only)

    // ---- phase 2: batched PV -- 8 waves x 2 et-tiles; each bfr feeds 4 attrs
    floatx4 acc[4][2];
#pragma unroll
    for (int al = 0; al < 4; ++al)
#pragma unroll
        for (int i = 0; i < 2; ++i) acc[al][i] = (floatx4){0.f, 0.f, 0.f, 0.f};

    for (int kc = 0; kc < 16; ++kc) {
        short8 bfr[2];
#pragma unroll
        for (int i = 0; i < 2; ++i)
            bfr[i] = *(const short8*)(sentFB +
                (((size_t)(bb * 16 + wv * 2 + i) * 16 + kc) << 9) + lane * 8);
#pragma unroll
        for (int al = 0; al < 4; ++al) {
            short8 afr = *(const short8*)(Pb + al * 8192 + l16 * 512 +
                (((kc * 4 + quad) ^ (l16 & 7)) << 3));
#pragma unroll
            for (int i = 0; i < 2; ++i)
                acc[al][i] = mfma16(afr, bfr[i], acc[al][i]);
        }
    }
    barrier_lds();   // all PV Pb-reads drained before Xb2 overwrites region

    // ---- phase 3: epilogue x4 -- Xb2[al] frag layout (R17-verified):
    //   t' = a*64 + t0/8 + g, k' = (tl&7)*256 + e
#pragma unroll
    for (int al = 0; al < 4; ++al) {
        float av = atr[bb * At + a0 + al];
#pragma unroll
        for (int i = 0; i < 2; ++i) {
            int W16 = wv * 2 + i;                 // e / 16
            int kcb = W16 >> 1;
            int qp  = (W16 & 1) * 2 + (l16 >> 3);
            int jp  = l16 & 7;
#pragma unroll
            for (int r = 0; r < 4; ++r) {
                int tl = quad * 4 + r;
                Xb2[al * 4096 + (((tl & 7) * 8 + kcb) << 6) + qp * 16
                    + ((tl >> 3) << 3) + jp] = f2bf(av * acc[al][i][r]);
            }
        }
    }
    barrier_lds();   // Xb2 visible before copy reads (LDS only)

    // ---- Xb2 -> XwsF frag blocks (TPT = a*4 + t0/128), rows L, L+1.
    // 512 thr: kc = tid>>3 (0..63), q8 = tid&7 -> one short8 each per attr.
#pragma unroll
    for (int al = 0; al < 4; ++al) {
        int a = a0 + al;
        int kc = tid >> 3, q8 = tid & 7;
        int TPT = (a << 2) + (t0 >> 7);
        size_t base = (((size_t)(bb * 32 + TPT)) * 64 + kc) * 512;
        short8 v = *(const short8*)(Xb2 + al * 4096 + (kc << 6)
                                    + (q8 >> 1) * 16 + (q8 & 1) * 8);
        *(short8*)(XwsF + base + ((q8 >> 1) * 16 + L + (q8 & 1)) * 8) = v;
    }
}

// ---- K3: out = Xr @ W^T + bias. LDS-free streaming GEMM, Mt=2 x Nt=2 -----
// 512 blocks (16 bb x 16 TPT-pairs x 2 n-halves), bb-major XCD swizzle.
// Each wave: 2 TPT rows-tiles x 2 nt col-tiles; every A-frag and B-frag
// load feeds 2 MFMAs (loads/MFMA 1.0; L2 768->512MB). Per-output-element
// kc accumulation order unchanged -> bitwise-identical.
__global__ __launch_bounds__(256) void k_out(const unsigned short* __restrict__ XwsF,
                                             const unsigned short* __restrict__ Wp,
                                             const float* __restrict__ bias,
                                             float* __restrict__ out) {
    int hw = blockIdx.x;                    // 512, 512%8==0 -> bijective
    int logical = (hw & 7) * 64 + (hw >> 3);
    int bb   = logical >> 5;                // 16 (2 per XCD)
    int TPT0 = ((logical >> 1) & 15) * 2;   // 0,2,..,30
    int nh   = logical & 1;                 // n half
    int tid = threadIdx.x;
    int wv = tid >> 6, lane = tid & 63, quad = lane >> 4, l16 = lane & 15;

    const unsigned short* A0 = XwsF + ((size_t)(bb * 32 + TPT0)) * 64 * 512 + lane * 8;
    const unsigned short* A1 = A0 + 64 * 512;
    floatx4 oacc[2][2];
#pragma unroll
    for (int m = 0; m < 2; ++m)
#pragma unroll
        for (int i = 0; i < 2; ++i) oacc[m][i] = (floatx4){0.f, 0.f, 0.f, 0.f};
    int nt0 = nh * 8 + wv * 2;
#pragma unroll 4
    for (int kc = 0; kc < 64; ++kc) {
        short8 a0 = *(const short8*)(A0 + kc * 512);
        short8 a1 = *(const short8*)(A1 + kc * 512);
#pragma unroll
        for (int i = 0; i < 2; ++i) {
            short8 bf = *(const short8*)(Wp +
                (((size_t)(nt0 + i) * 64 + kc) << 9) + lane * 8);
            oacc[0][i] = mfma16(a0, bf, oacc[0][i]);
            oacc[1][i] = mfma16(a1, bf, oacc[1][i]);
        }
    }
#pragma unroll
    for (int m = 0; m < 2; ++m) {
#pragma unroll
        for (int i = 0; i < 2; ++i) {
            int n = (nt0 + i) * 16 + l16;
            float bv = bias[n];
#pragma unroll
            for (int r = 0; r < 4; ++r) {
                int tp = (TPT0 + m) * 16 + quad * 4 + r;
                out[((size_t)bb * Tt + tp) * Et + n] = oacc[m][i][r] + bv;
            }
        }
    }
}

extern "C" void kernel_launch(void* const* d_in, const int* in_sizes, int n_in,
                              void* d_out, int out_size, void* d_ws, size_t ws_size,
                              hipStream_t stream) {
    const float* sent = (const float*)d_in[0];   // f32 (B,T,E)
    const int*   mask = (const int*)d_in[1];     // int32 (B,T)
    const float* atr  = (const float*)d_in[2];   // f32 (B,A)
    const float* W    = (const float*)d_in[3];   // f32 (E, A*E)
    const float* bias = (const float*)d_in[4];   // f32 (E)

    float* out0  = (float*)d_out;                     // 2,097,152 f32
    float* attnf = out0 + (size_t)Bt * Tt * Et;       // 33,554,432 f32

    char* ws = (char*)d_ws;
    unsigned short* sentG  = (unsigned short*)(ws);             // 4 MB
    unsigned short* sentFB = (unsigned short*)(ws + 4194304);   // 4 MB
    unsigned short* Wp     = (unsigned short*)(ws + 8388608);   // 1 MB
    unsigned short* XwsF   = (unsigned short*)(ws + 9437184);   // 32 MB frag-major
    // total 42.99 MB (== R2/R9 proven-safe footprint)

    hipLaunchKernelGGL(k_prep_sent, dim3(Tt / 32, Et / 32, Bt), dim3(256), 0, stream,
                       sent, sentG, sentFB);
    hipLaunchKernelGGL(k_prep_w, dim3(16, 8), dim3(256), 0, stream, W, Wp);
    hipLaunchKernelGGL(k_attnpv, dim3(1024), dim3(512), 0, stream,
                       sentG, sentFB, mask, atr, attnf, XwsF);
    hipLaunchKernelGGL(k_out, dim3(512), dim3(256), 0, stream,
                       XwsF, Wp, bias, out0);
}